// Round 8
// baseline (7039.274 us; speedup 1.0000x reference)
//
#include <hip/hip_runtime.h>
#include <stdint.h>

// Problem constants
#define TT 256      // timesteps per phase
#define BB 256      // batch
#define II 128      // input dim
#define SS 256      // state dim
#define NTEAM 16    // row teams (16 batch rows each)
#define CGRP 16     // col-blocks per team
#define RB 16       // batch rows per role
#define CB 16       // state cols per role
#define NSTEP (2*TT)
#define NBLKG 64    // 64 blocks x 4 independent wave-roles = 256 roles

typedef _Float16 h16;
typedef _Float16 half8 __attribute__((ext_vector_type(8)));
typedef float f32x4 __attribute__((ext_vector_type(4)));
typedef unsigned int u32x4 __attribute__((ext_vector_type(4)));

// Exchange buffer: [parity][team][row 0..15][col_pair 0..127] of u64
//   u64 = { hi: step tag, lo: packed 2 x fp16 (even col in low half) }
// Tag-in-data => no flags, no drains, no barriers. Aligned 8B global accesses
// are single-copy atomic on AMDGPU. Parity reuse safe: producer writes step
// n+2 into a slot only after gathering all of s_{n+1}, which requires every
// team member to have finished READING s_n from that slot.
#define XROW 128
#define XTEAM (RB * XROW)        // 2048 u64 per team
#define XPAR  (NTEAM * XTEAM)    // 32768 u64 per parity

__device__ __forceinline__ float sigmoidf_(float z) {
    return __builtin_amdgcn_rcpf(1.0f + __expf(-z));
}
__device__ __forceinline__ float tanhf_(float z) {
    return 1.0f - 2.0f * __builtin_amdgcn_rcpf(1.0f + __expf(2.0f * z));
}

__device__ __forceinline__ uint64_t ld_ag64(const uint64_t* p) {
    return __hip_atomic_load(p, __ATOMIC_RELAXED, __HIP_MEMORY_SCOPE_AGENT);
}
__device__ __forceinline__ void st_ag64(uint64_t* p, uint64_t v) {
    __hip_atomic_store(p, v, __ATOMIC_RELAXED, __HIP_MEMORY_SCOPE_AGENT);
}

struct Ptrs {
    const float *x;
    const float *Wi, *Ui, *Bi, *Wf, *Uf, *Bf, *Wo, *Uo, *Bo, *Wg, *Ug, *Bg;
    float* out;
    uint32_t* ws;
};

__global__ __launch_bounds__(256, 1) void lstm_wave(Ptrs p) {
    const int tid  = threadIdx.x;
    const int wid  = tid >> 6;             // wave id in block: 4 independent roles
    const int lane = tid & 63;
    const int role = blockIdx.x * 4 + wid; // 0..255
    const int team = role >> 4;            // batch rows [team*16, +16)
    const int cb   = role & 15;            // state cols [cb*16, +16)
    const int r0   = team * RB;
    const int c0   = cb * CB;
    const int lrow = lane & 15;            // A-row / C-col for this lane
    const int lgrp = lane >> 4;            // 0..3
    const int lk8  = lgrp * 8;             // k sub-offset within 32-chunk

    uint64_t* xch   = (uint64_t*)p.ws;
    uint64_t* slot0 = xch + (size_t)team * XTEAM;          // parity 0
    uint64_t* slot1 = xch + XPAR + (size_t)team * XTEAM;   // parity 1

    const float* Uptr[4] = {p.Ui, p.Uf, p.Uo, p.Ug};
    const float* Wptr[4] = {p.Wi, p.Wf, p.Wo, p.Wg};
    const float* Bptr[4] = {p.Bi, p.Bf, p.Bo, p.Bg};

    // ---- preload ALL 4 gates' B-fragments for this col-block ----
    // B layout (16x16x32): lane holds B[k=(lane>>4)*8+q][col=lane&15]
    half8 bU[4][8];
#pragma unroll
    for (int g = 0; g < 4; ++g) {
        const float* Ug = Uptr[g];
#pragma unroll
        for (int kc = 0; kc < 8; ++kc)
#pragma unroll
            for (int q = 0; q < 8; ++q)
                bU[g][kc][q] = (h16)Ug[(size_t)(kc * 32 + lk8 + q) * SS + c0 + lrow];
    }
    half8 bW[4][4];
#pragma unroll
    for (int g = 0; g < 4; ++g) {
        const float* Wg = Wptr[g];
#pragma unroll
        for (int kc = 0; kc < 4; ++kc)
#pragma unroll
            for (int q = 0; q < 8; ++q)
                bW[g][kc][q] = (h16)Wg[(size_t)(kc * 32 + lk8 + q) * SS + c0 + lrow];
    }
    float bias[4];
#pragma unroll
    for (int g = 0; g < 4; ++g) bias[g] = Bptr[g][c0 + lrow];

    // cell state: lane owns cells (row = lgrp*4+q, col = lrow), q=0..3
    float cst[4] = {0.f, 0.f, 0.f, 0.f};

    for (int n = 1; n <= NSTEP; ++n) {
        const bool enc = (n <= TT);

        // ---- gather s_{n-1}: issue all 32 loads FIRST (critical path) ----
        uint64_t gv[8][4];
        const uint64_t* gb = (((n - 1) & 1) ? slot1 : slot0) + (size_t)lrow * XROW;
        if (n >= 2) {
#pragma unroll
            for (int kc = 0; kc < 8; ++kc)
#pragma unroll
                for (int j = 0; j < 4; ++j)
                    gv[kc][j] = ld_ag64(gb + kc * 16 + lgrp * 4 + j);   // 32 in flight
        }

        // ---- x-tile loads (fly under the gather RT) ----
        float4 xv[8];
        if (enc) {
            const float* xp = p.x + ((size_t)(n - 1) * BB + r0 + lrow) * II;
#pragma unroll
            for (int kc = 0; kc < 4; ++kc) {
                xv[2*kc]   = ((const float4*)(xp + kc * 32 + lk8))[0];
                xv[2*kc+1] = ((const float4*)(xp + kc * 32 + lk8))[1];
            }
        }

        f32x4 acc[4];
#pragma unroll
        for (int g = 0; g < 4; ++g) acc[g] = (f32x4){0.f, 0.f, 0.f, 0.f};

        // ---- x @ W contribution (encode only; independent of gather) ----
        if (enc) {
#pragma unroll
            for (int kc = 0; kc < 4; ++kc) {
                half8 xa;
                xa[0] = (h16)xv[2*kc].x;   xa[1] = (h16)xv[2*kc].y;
                xa[2] = (h16)xv[2*kc].z;   xa[3] = (h16)xv[2*kc].w;
                xa[4] = (h16)xv[2*kc+1].x; xa[5] = (h16)xv[2*kc+1].y;
                xa[6] = (h16)xv[2*kc+1].z; xa[7] = (h16)xv[2*kc+1].w;
#pragma unroll
                for (int g = 0; g < 4; ++g)
                    acc[g] = __builtin_amdgcn_mfma_f32_16x16x32_f16(xa, bW[g][kc], acc[g], 0, 0, 0);
            }
        }

        // ---- batched-parallel retry: each pass re-issues ALL stale loads
        //      back-to-back (exec-masked, independent -> one wait), then
        //      re-checks. Each pass ~1 RT regardless of stale count. ----
        if (n >= 2) {
            const uint32_t want = (uint32_t)(n - 1);
            bool any = true;
            while (any) {
                any = false;
#pragma unroll
                for (int kc = 0; kc < 8; ++kc)
#pragma unroll
                    for (int j = 0; j < 4; ++j)
                        any |= ((uint32_t)(gv[kc][j] >> 32) != want);
                if (any) {
#pragma unroll
                    for (int kc = 0; kc < 8; ++kc)
#pragma unroll
                        for (int j = 0; j < 4; ++j)
                            if ((uint32_t)(gv[kc][j] >> 32) != want)
                                gv[kc][j] = ld_ag64(gb + kc * 16 + lgrp * 4 + j);
                }
            }
            // ---- s @ U MFMAs ----
#pragma unroll
            for (int kc = 0; kc < 8; ++kc) {
                u32x4 t;
                t.x = (uint32_t)gv[kc][0]; t.y = (uint32_t)gv[kc][1];
                t.z = (uint32_t)gv[kc][2]; t.w = (uint32_t)gv[kc][3];
                half8 a = __builtin_bit_cast(half8, t);
#pragma unroll
                for (int g = 0; g < 4; ++g)
                    acc[g] = __builtin_amdgcn_mfma_f32_16x16x32_f16(a, bU[g][kc], acc[g], 0, 0, 0);
            }
        }

        // ---- gates + state update, all in registers ----
        float sv[4], ov[4];
#pragma unroll
        for (int q = 0; q < 4; ++q) {
            float zi = acc[0][q] + bias[0];
            float zf = acc[1][q] + bias[1];
            float zo = acc[2][q] + bias[2];
            float zg = acc[3][q] + bias[3];
            float ig = sigmoidf_(zi), fg = sigmoidf_(zf);
            float og = sigmoidf_(zo), gg = tanhf_(zg);
            cst[q] = cst[q] * fg + gg * ig;
            sv[q] = tanhf_(cst[q]) * og;
            ov[q] = og;
        }

        // ---- publish s_n FIRST (critical path for the team) ----
        if (n < NSTEP) {
            uint64_t* pb = ((n & 1) ? slot1 : slot0);
            const uint64_t tag = (uint64_t)(uint32_t)n << 32;
#pragma unroll
            for (int q = 0; q < 4; ++q) {
                float so = __shfl_xor(sv[q], 1);
                if ((lane & 1) == 0) {
                    uint16_t lo = __builtin_bit_cast(uint16_t, (h16)sv[q]);
                    uint16_t hi = __builtin_bit_cast(uint16_t, (h16)so);
                    uint64_t pk = tag | (uint64_t)((uint32_t)lo | ((uint32_t)hi << 16));
                    st_ag64(pb + (size_t)(lgrp * 4 + q) * XROW + cb * 8 + (lrow >> 1), pk);
                }
            }
        }

        // ---- output store after publish (off the team's critical path) ----
        if (!enc) {
            const int d = n - TT - 1;
#pragma unroll
            for (int q = 0; q < 4; ++q)
                p.out[((size_t)d * BB + r0 + lgrp * 4 + q) * SS + c0 + lrow] = ov[q];
        }
    }
}

extern "C" void kernel_launch(void* const* d_in, const int* in_sizes, int n_in,
                              void* d_out, int out_size, void* d_ws, size_t ws_size,
                              hipStream_t stream) {
    Ptrs p;
    p.x  = (const float*)d_in[0];
    p.Wi = (const float*)d_in[1];  p.Ui = (const float*)d_in[2];  p.Bi = (const float*)d_in[3];
    p.Wf = (const float*)d_in[4];  p.Uf = (const float*)d_in[5];  p.Bf = (const float*)d_in[6];
    p.Wo = (const float*)d_in[7];  p.Uo = (const float*)d_in[8];  p.Bo = (const float*)d_in[9];
    p.Wg = (const float*)d_in[10]; p.Ug = (const float*)d_in[11]; p.Bg = (const float*)d_in[12];
    p.out = (float*)d_out;
    p.ws  = (uint32_t*)d_ws;

    // zero tag words each launch -> no stale-tag acceptance, replay-safe
    hipMemsetAsync(d_ws, 0, (size_t)2 * XPAR * sizeof(uint64_t), stream);

    // Proven 64x256 coop shape; fallback to plain launch if rejected (the
    // tag protocol needs no grid-wide primitives, only de-facto co-residency
    // of 64 blocks on 256 CUs).
    void* args[] = {&p};
    hipError_t e = hipLaunchCooperativeKernel(lstm_wave, dim3(NBLKG), dim3(256),
                                              args, 0, stream);
    if (e != hipSuccess) {
        hipLaunchKernelGGL(lstm_wave, dim3(NBLKG), dim3(256), 0, stream, p);
    }
}

// Round 9
// 1514.723 us; speedup vs baseline: 4.6472x; 4.6472x over previous
//
#include <hip/hip_runtime.h>
#include <stdint.h>

// Problem constants
#define TT 256      // timesteps per phase
#define BB 256      // batch
#define II 128      // input dim
#define SS 256      // state dim
#define NTEAM 16    // row teams (16 batch rows each)
#define CGRP 16     // col-blocks per team
#define RB 16       // batch rows per block
#define CB 16       // state cols per block
#define NSTEP (2*TT)
#define NBLK (NTEAM*CGRP)   // 256 blocks x 256 threads (r1-proven shape)

typedef _Float16 h16;
typedef _Float16 half8 __attribute__((ext_vector_type(8)));
typedef float f32x4 __attribute__((ext_vector_type(4)));

#define SBP 264     // s_buf padded row stride (halves)
#define XBP 136     // xbuf padded row stride (halves)

// Exchange: [parity][team][row 0..15][col_pair 0..127] of u64
//   u64 = { hi: step tag, lo: 2 x fp16 (even col in low half) }
// Tag-in-data: no flags, no drains, no extra barriers. Aligned 8B accesses
// are single-copy atomic. Parity-lap safety: a producer writes s_{n+2} into
// a slot only after gathering ALL of s_{n+1}, which requires every team
// member to have published s_{n+1}, which happens only after they finished
// READING s_n from that slot. (Protocol correctness proven in r7/r8 runs.)
#define XROW 128
#define XTEAM (RB * XROW)        // 2048 u64 per team
#define XPAR  (NTEAM * XTEAM)    // 32768 u64 per parity

__device__ __forceinline__ float sigmoidf_(float z) {
    return __builtin_amdgcn_rcpf(1.0f + __expf(-z));
}
__device__ __forceinline__ float tanhf_(float z) {
    return 1.0f - 2.0f * __builtin_amdgcn_rcpf(1.0f + __expf(2.0f * z));
}

// serial (proven-correct, slow) agent-scope primitives
__device__ __forceinline__ uint64_t ld_ag64(const uint64_t* p) {
    return __hip_atomic_load(p, __ATOMIC_RELAXED, __HIP_MEMORY_SCOPE_AGENT);
}
__device__ __forceinline__ void st_ag64(uint64_t* p, uint64_t v) {
    __hip_atomic_store(p, v, __ATOMIC_RELAXED, __HIP_MEMORY_SCOPE_AGENT);
}

// BATCHED device-coherent gather: 8 independent loads in flight, ONE wait.
// sc1 = device scope on gfx950 MUBUF/FLAT (bypass non-coherent caches).
__device__ __forceinline__ void ld8u64_sc1(const uint64_t* p, uint64_t* v) {
    asm volatile(
        "global_load_dwordx2 %0, %8, off sc1\n\t"
        "global_load_dwordx2 %1, %8, off offset:8 sc1\n\t"
        "global_load_dwordx2 %2, %8, off offset:16 sc1\n\t"
        "global_load_dwordx2 %3, %8, off offset:24 sc1\n\t"
        "global_load_dwordx2 %4, %8, off offset:32 sc1\n\t"
        "global_load_dwordx2 %5, %8, off offset:40 sc1\n\t"
        "global_load_dwordx2 %6, %8, off offset:48 sc1\n\t"
        "global_load_dwordx2 %7, %8, off offset:56 sc1\n\t"
        "s_waitcnt vmcnt(0)"
        : "=&v"(v[0]), "=&v"(v[1]), "=&v"(v[2]), "=&v"(v[3]),
          "=&v"(v[4]), "=&v"(v[5]), "=&v"(v[6]), "=&v"(v[7])
        : "v"(p) : "memory");
}

struct Ptrs {
    const float *x;
    const float *Wi, *Ui, *Bi, *Wf, *Uf, *Bf, *Wo, *Uo, *Bo, *Wg, *Ug, *Bg;
    float* out;
    uint32_t* ws;
};

__global__ __launch_bounds__(256, 1) void lstm_persist(Ptrs p) {
    const int bid  = blockIdx.x;
    const int tid  = threadIdx.x;
    const int wave = tid >> 6;            // gate: 0=i 1=f 2=o 3=g
    const int lane = tid & 63;
    const int lrow = lane & 15;           // A-row / B-col within tile
    const int lk8  = (lane >> 4) * 8;     // k sub-offset within 32-chunk
    const int erow = tid >> 4;            // elementwise (row,col) ownership
    const int ecol = tid & 15;

    const int team = bid >> 4;            // batch rows [team*16, +16)
    const int c    = bid & 15;            // col block  [c*16, +16)
    const int r0   = team * RB;
    const int c0   = c * CB;

    __shared__ __align__(16) h16 s_buf[RB * SBP];
    __shared__ __align__(16) h16 xbuf[RB * XBP];
    __shared__ float zbuf[4][16][17];
    __shared__ float biasLds[4][16];

    uint64_t* xch   = (uint64_t*)p.ws;
    uint64_t* slot0 = xch + (size_t)team * XTEAM;          // parity 0
    uint64_t* slot1 = xch + XPAR + (size_t)team * XTEAM;   // parity 1

    const float* Uptr[4] = {p.Ui, p.Uf, p.Uo, p.Ug};
    const float* Wptr[4] = {p.Wi, p.Wf, p.Wo, p.Wg};
    const float* Bptr[4] = {p.Bi, p.Bf, p.Bo, p.Bg};

    if (tid < 64) biasLds[tid >> 4][tid & 15] = Bptr[tid >> 4][c0 + (tid & 15)];
    for (int idx = tid; idx < RB * SBP; idx += 256) s_buf[idx] = (h16)0.0f;

    // Preload B-operand fragments for this wave's gate (r1-proven layout):
    // B (16x16x32): lane holds B[k=(lane>>4)*8+q][col=lane&15]
    const float* Ug = Uptr[wave];
    const float* Wg = Wptr[wave];
    half8 bU[8];
#pragma unroll
    for (int kc = 0; kc < 8; ++kc)
#pragma unroll
        for (int q = 0; q < 8; ++q)
            bU[kc][q] = (h16)Ug[(size_t)(kc * 32 + lk8 + q) * SS + c0 + lrow];
    half8 bW[4];
#pragma unroll
    for (int kc = 0; kc < 4; ++kc)
#pragma unroll
        for (int q = 0; q < 8; ++q)
            bW[kc][q] = (h16)Wg[(size_t)(kc * 32 + lk8 + q) * SS + c0 + lrow];

    float cst = 0.0f;   // cell state owned by this thread: (erow, ecol)

    // ---- stage x tile for t=0; prefetch t=1 ----
    float4 pa, pb;
    {
        const float* xp = p.x + ((size_t)0 * BB + r0 + erow) * II + ecol * 8;
        pa = ((const float4*)xp)[0];
        pb = ((const float4*)xp)[1];
        half8 h;
        h[0]=(h16)pa.x; h[1]=(h16)pa.y; h[2]=(h16)pa.z; h[3]=(h16)pa.w;
        h[4]=(h16)pb.x; h[5]=(h16)pb.y; h[6]=(h16)pb.z; h[7]=(h16)pb.w;
        *(half8*)&xbuf[erow * XBP + ecol * 8] = h;
        const float* xp1 = p.x + ((size_t)1 * BB + r0 + erow) * II + ecol * 8;
        pa = ((const float4*)xp1)[0];
        pb = ((const float4*)xp1)[1];
    }
    __syncthreads();

    for (int n = 1; n <= NSTEP; ++n) {
        const bool enc = (n <= TT);

        // ---- MFMA: z[16x16] for gate `wave` ----
        f32x4 acc = {0.f, 0.f, 0.f, 0.f};
#pragma unroll
        for (int kc = 0; kc < 8; ++kc) {
            half8 a = *(const half8*)&s_buf[lrow * SBP + kc * 32 + lk8];
            acc = __builtin_amdgcn_mfma_f32_16x16x32_f16(a, bU[kc], acc, 0, 0, 0);
        }
        if (enc) {
#pragma unroll
            for (int kc = 0; kc < 4; ++kc) {
                half8 a = *(const half8*)&xbuf[lrow * XBP + kc * 32 + lk8];
                acc = __builtin_amdgcn_mfma_f32_16x16x32_f16(a, bW[kc], acc, 0, 0, 0);
            }
        }
        // C/D layout: col=lane&15, row=(lane>>4)*4+reg (m89-verified)
#pragma unroll
        for (int q = 0; q < 4; ++q)
            zbuf[wave][(lane >> 4) * 4 + q][lrow] = acc[q];
        __syncthreads();   // barrier A: zbuf ready; s_buf/xbuf reads done

        // ---- elementwise gates / state update ----
        float zi = zbuf[0][erow][ecol] + biasLds[0][ecol];
        float zf = zbuf[1][erow][ecol] + biasLds[1][ecol];
        float zo = zbuf[2][erow][ecol] + biasLds[2][ecol];
        float zg = zbuf[3][erow][ecol] + biasLds[3][ecol];
        float ig = sigmoidf_(zi), fg = sigmoidf_(zf);
        float og = sigmoidf_(zo), gg = tanhf_(zg);
        cst = cst * fg + gg * ig;
        float sv = tanhf_(cst) * og;

        h16 svh = (h16)sv;
        s_buf[erow * SBP + c * 16 + ecol] = svh;   // own slice direct to LDS

        if (n < NSTEP) {
            uint64_t* slotP = (n & 1) ? slot1 : slot0;

            // ---- publish s_n: tagged u64, fire-and-forget ----
            float so = __shfl_xor(sv, 1);
            if ((tid & 1) == 0) {
                uint16_t lo = __builtin_bit_cast(uint16_t, svh);
                uint16_t hi = __builtin_bit_cast(uint16_t, (h16)so);
                uint64_t pk = ((uint64_t)(uint32_t)n << 32)
                            | (uint64_t)((uint32_t)lo | ((uint32_t)hi << 16));
                st_ag64(slotP + (size_t)erow * XROW + c * 8 + (ecol >> 1), pk);
            }

            // ---- output store (off the team's critical path) ----
            if (!enc) {
                const int d = n - TT - 1;
                p.out[((size_t)d * BB + r0 + erow) * SS + c0 + ecol] = og;
            }

            // ---- gather s_n: batched 8-load passes, ~1 RT per pass ----
            if (ecol != c) {
                const uint64_t* gp = slotP + (size_t)erow * XROW + ecol * 8;
                const uint32_t want = (uint32_t)n;
                uint64_t gv[8];
                ld8u64_sc1(gp, gv);
                bool fresh = false;
                for (int pass = 0; pass < 4096 && !fresh; ++pass) {
                    fresh = true;
#pragma unroll
                    for (int j = 0; j < 8; ++j)
                        fresh = fresh && ((uint32_t)(gv[j] >> 32) == want);
                    if (!fresh) ld8u64_sc1(gp, gv);
                }
                if (!fresh) {   // proven-correct fallback (never hangs)
#pragma unroll
                    for (int j = 0; j < 8; ++j)
                        while ((uint32_t)(gv[j] >> 32) != want)
                            gv[j] = ld_ag64(gp + j);
                }
                uint4 q0 = make_uint4((uint32_t)gv[0], (uint32_t)gv[1],
                                      (uint32_t)gv[2], (uint32_t)gv[3]);
                uint4 q1 = make_uint4((uint32_t)gv[4], (uint32_t)gv[5],
                                      (uint32_t)gv[6], (uint32_t)gv[7]);
                *(uint4*)&s_buf[erow * SBP + ecol * 16]     = q0;
                *(uint4*)&s_buf[erow * SBP + ecol * 16 + 8] = q1;
            }

            // ---- stage next x tile; prefetch one further ahead ----
            if (n < TT) {
                half8 h;
                h[0]=(h16)pa.x; h[1]=(h16)pa.y; h[2]=(h16)pa.z; h[3]=(h16)pa.w;
                h[4]=(h16)pb.x; h[5]=(h16)pb.y; h[6]=(h16)pb.z; h[7]=(h16)pb.w;
                *(half8*)&xbuf[erow * XBP + ecol * 8] = h;
                if (n + 1 < TT) {
                    const float* xp = p.x + ((size_t)(n + 1) * BB + r0 + erow) * II + ecol * 8;
                    pa = ((const float4*)xp)[0];
                    pb = ((const float4*)xp)[1];
                }
            }
            __syncthreads();   // barrier B: s_buf/xbuf complete for step n+1
        } else if (!enc) {
            const int d = n - TT - 1;
            p.out[((size_t)d * BB + r0 + erow) * SS + c0 + ecol] = og;
        }
    }
}

extern "C" void kernel_launch(void* const* d_in, const int* in_sizes, int n_in,
                              void* d_out, int out_size, void* d_ws, size_t ws_size,
                              hipStream_t stream) {
    Ptrs p;
    p.x  = (const float*)d_in[0];
    p.Wi = (const float*)d_in[1];  p.Ui = (const float*)d_in[2];  p.Bi = (const float*)d_in[3];
    p.Wf = (const float*)d_in[4];  p.Uf = (const float*)d_in[5];  p.Bf = (const float*)d_in[6];
    p.Wo = (const float*)d_in[7];  p.Uo = (const float*)d_in[8];  p.Bo = (const float*)d_in[9];
    p.Wg = (const float*)d_in[10]; p.Ug = (const float*)d_in[11]; p.Bg = (const float*)d_in[12];
    p.out = (float*)d_out;
    p.ws  = (uint32_t*)d_ws;

    // zero tag words each launch -> no stale-tag acceptance, replay-safe
    hipMemsetAsync(d_ws, 0, (size_t)2 * XPAR * sizeof(uint64_t), stream);

    // r1-proven coop shape; fallback to plain launch (protocol needs only
    // de-facto co-residency: 256 blocks on 256 CUs).
    void* args[] = {&p};
    hipError_t e = hipLaunchCooperativeKernel(lstm_persist, dim3(NBLK), dim3(256),
                                              args, 0, stream);
    if (e != hipSuccess) {
        hipLaunchKernelGGL(lstm_persist, dim3(NBLK), dim3(256), 0, stream, p);
    }
}